// Round 1
// baseline (216.420 us; speedup 1.0000x reference)
//
#include <hip/hip_runtime.h>
#include <hip/hip_bf16.h>
#include <math.h>

#define EPSV 1e-5f

typedef __attribute__((ext_vector_type(4))) float f32x4;
typedef __attribute__((ext_vector_type(8))) short bf16x8;

__device__ __forceinline__ unsigned short f2b(float x) {
  union { float f; unsigned int u; } v; v.f = x;
  unsigned int r = v.u + 0x7FFFu + ((v.u >> 16) & 1u);
  return (unsigned short)(r >> 16);
}
__device__ __forceinline__ float b2f(unsigned short h) {
  union { float f; unsigned int u; } v; v.u = ((unsigned int)h) << 16;
  return v.f;
}

// block = 256 threads = 4 waves; sbuf must have 4 floats
__device__ __forceinline__ float block_reduce_sum(float v, float* sbuf) {
  #pragma unroll
  for (int off = 32; off; off >>= 1) v += __shfl_xor(v, off);
  __syncthreads();
  if ((threadIdx.x & 63) == 0) sbuf[threadIdx.x >> 6] = v;
  __syncthreads();
  return sbuf[0] + sbuf[1] + sbuf[2] + sbuf[3];
}

// ---------------- kernel 1: V[b,n, p*128+d] = l2norm_d(context*w_p), bf16 ----
// grid = B*N blocks, 64 threads; each lane handles d and d+64.
__global__ __launch_bounds__(64) void vkern(const float* __restrict__ ctx,
                                            const float* __restrict__ wt,
                                            unsigned short* __restrict__ V) {
  const int bn = blockIdx.x;
  const int l = threadIdx.x;
  const float* c = ctx + (size_t)bn * 128;
  const float c0 = c[l], c1 = c[l + 64];
  unsigned short* vout = V + (size_t)bn * 2048;
  #pragma unroll
  for (int p = 0; p < 16; ++p) {
    const float a0 = c0 * wt[p * 128 + l];
    const float a1 = c1 * wt[p * 128 + l + 64];
    float ss = a0 * a0 + a1 * a1;
    #pragma unroll
    for (int off = 32; off; off >>= 1) ss += __shfl_xor(ss, off);
    const float inv = 1.0f / fmaxf(sqrtf(ss), 1e-12f);
    vout[p * 128 + l] = f2b(a0 * inv);
    vout[p * 128 + l + 64] = f2b(a1 * inv);
  }
}

// ---------------- kernel 2: SW[b,n,m] row-l2norm'd, bf16 ---------------------
// grid = B*N blocks, 256 threads, 4 cols per thread (N=1024)
__global__ __launch_bounds__(256) void swkern(const float* __restrict__ speed,
                                              const float* __restrict__ uva,
                                              const float* __restrict__ accu,
                                              const float* __restrict__ accv,
                                              const float* __restrict__ uvaACC,
                                              const float* __restrict__ angle,
                                              const float* __restrict__ dist,
                                              unsigned short* __restrict__ SW,
                                              int N) {
  __shared__ float sbuf[4];
  const int bn = blockIdx.x;
  const int n = bn % N;
  const int t = threadIdx.x;
  const float ua = uva[bn];
  const float sp = fabsf(speed[bn]);
  const float au = accu[bn], av = accv[bn];
  const float ta = sqrtf(au * au + av * av + EPSV) * fabsf(cosf(uvaACC[bn] - ua));
  float vals[4];
  float ss = 0.0f;
  #pragma unroll
  for (int i = 0; i < 4; ++i) {
    const int m = t + i * 256;
    float cv = cosf(angle[(size_t)n * N + m] - ua);
    if (m == n) cv += 0.5f * ta;  // sigma * acc_part inside the abs
    const float v = sp * fabsf(cv) / (dist[(size_t)n * N + m] + EPSV);
    vals[i] = v;
    ss += v * v;
  }
  ss = block_reduce_sum(ss, sbuf);
  const float inv = 1.0f / fmaxf(sqrtf(ss), 1e-12f);
  unsigned short* o = SW + (size_t)bn * N;
  #pragma unroll
  for (int i = 0; i < 4; ++i) o[t + i * 256] = f2b(vals[i] * inv);
}

// ---------------- kernel 3/4: C[b] = epilogue(scale * A_b · A_bᵀ) ------------
// 128x128 tile, BK=32, 4 waves (2x2), each wave 64x64 via 4x4 of 16x16x32.
// MODE 0: relu (attention).  MODE 1: +EPS (y).
template <int MODE>
__global__ __launch_bounds__(256) void gemm_bt(const unsigned short* __restrict__ A,
                                               float* __restrict__ C,
                                               int N, int K, float scale) {
  __shared__ __align__(16) unsigned short As[128 * 32];
  __shared__ __align__(16) unsigned short Bs[128 * 32];
  const int b = blockIdx.z;
  const int n0 = blockIdx.x * 128;
  const int m0 = blockIdx.y * 128;
  const unsigned short* Ab = A + (size_t)b * N * K;
  const int tid = threadIdx.x;
  const int lane = tid & 63;
  const int wid = tid >> 6;
  const int wm = (wid >> 1) * 64;
  const int wn = (wid & 1) * 64;
  f32x4 acc[4][4] = {};

  for (int k0 = 0; k0 < K; k0 += 32) {
    // stage A-tile (rows m0+*) and B-tile (rows n0+*), 16B per thread per issue
    #pragma unroll
    for (int i = 0; i < 2; ++i) {
      const int idx = i * 256 + tid;   // 16B chunk id, 0..511
      const int row = idx >> 2;        // 64B (32 bf16) per row
      const int cq = (idx & 3) * 8;    // bf16 offset within row
      __builtin_amdgcn_global_load_lds(
          (const __attribute__((address_space(1))) unsigned int*)(Ab + (size_t)(m0 + row) * K + k0 + cq),
          (__attribute__((address_space(3))) unsigned int*)(As + idx * 8), 16, 0, 0);
      __builtin_amdgcn_global_load_lds(
          (const __attribute__((address_space(1))) unsigned int*)(Ab + (size_t)(n0 + row) * K + k0 + cq),
          (__attribute__((address_space(3))) unsigned int*)(Bs + idx * 8), 16, 0, 0);
    }
    __syncthreads();  // compiler drains vmcnt before s_barrier

    bf16x8 af[4], bfr[4];
    #pragma unroll
    for (int i = 0; i < 4; ++i)
      af[i] = *(const bf16x8*)(As + (wm + i * 16 + (lane & 15)) * 32 + (lane >> 4) * 8);
    #pragma unroll
    for (int j = 0; j < 4; ++j)
      bfr[j] = *(const bf16x8*)(Bs + (wn + j * 16 + (lane & 15)) * 32 + (lane >> 4) * 8);
    #pragma unroll
    for (int i = 0; i < 4; ++i)
      #pragma unroll
      for (int j = 0; j < 4; ++j)
        acc[i][j] = __builtin_amdgcn_mfma_f32_16x16x32_bf16(af[i], bfr[j], acc[i][j], 0, 0, 0);
    __syncthreads();  // protect LDS from next iteration's staging
  }

  float* Cb = C + (size_t)b * N * N;
  #pragma unroll
  for (int i = 0; i < 4; ++i) {
    #pragma unroll
    for (int r = 0; r < 4; ++r) {
      const int row = m0 + wm + i * 16 + (lane >> 4) * 4 + r;
      #pragma unroll
      for (int j = 0; j < 4; ++j) {
        const int col = n0 + wn + j * 16 + (lane & 15);
        float v = acc[i][j][r] * scale;
        v = (MODE == 0) ? fmaxf(v, 0.0f) : (v + EPSV);
        Cb[(size_t)row * N + col] = v;
      }
    }
  }
}

// ---------------- kernel 5: finisher ----------------------------------------
// per (b,n) row: ynorm, t = |0.5*sw + sqrt(y/||y||)| + EPS, tnorm, out *= t/||t||
__global__ __launch_bounds__(256) void finkern(const float* __restrict__ Y,
                                               const unsigned short* __restrict__ SW,
                                               float* __restrict__ OUT,
                                               int N) {
  __shared__ float sbuf[4];
  const int bn = blockIdx.x;
  const int t = threadIdx.x;
  const float* y = Y + (size_t)bn * N;
  const unsigned short* sw = SW + (size_t)bn * N;
  float* o = OUT + (size_t)bn * N;

  float yv[4];
  float ss = 0.0f;
  #pragma unroll
  for (int i = 0; i < 4; ++i) {
    yv[i] = y[t + i * 256];
    ss += yv[i] * yv[i];
  }
  ss = block_reduce_sum(ss, sbuf);
  const float invy = 1.0f / fmaxf(sqrtf(ss), 1e-12f);

  float tv[4];
  float st = 0.0f;
  #pragma unroll
  for (int i = 0; i < 4; ++i) {
    const float swf = b2f(sw[t + i * 256]);
    const float x = fabsf(0.5f * swf + sqrtf(yv[i] * invy)) + EPSV;
    tv[i] = x;
    st += x * x;
  }
  st = block_reduce_sum(st, sbuf);
  const float invt = 1.0f / fmaxf(sqrtf(st), 1e-12f);

  #pragma unroll
  for (int i = 0; i < 4; ++i) o[t + i * 256] *= tv[i] * invt;
}

extern "C" void kernel_launch(void* const* d_in, const int* in_sizes, int n_in,
                              void* d_out, int out_size, void* d_ws, size_t ws_size,
                              hipStream_t stream) {
  const float* ctx        = (const float*)d_in[0];
  const float* acc_u      = (const float*)d_in[1];
  const float* acc_v      = (const float*)d_in[2];
  const float* uv_angle   = (const float*)d_in[3];
  const float* uv_angleACC= (const float*)d_in[4];
  const float* speed      = (const float*)d_in[5];
  // d_in[6] = isPhy (unused by the reference computation)
  const float* dist       = (const float*)d_in[7];
  const float* angle      = (const float*)d_in[8];
  const float* wt         = (const float*)d_in[9];

  const int B = 8, N = 1024, P = 16, D = 128;
  const int K1 = P * D;  // 2048

  // ws layout: region0 [0, 33.5MB): V bf16, later reused as Y f32 (same size)
  //            region1 [33.5MB, 50.3MB): SW bf16
  unsigned short* V  = (unsigned short*)d_ws;
  float*          Y  = (float*)d_ws;
  unsigned short* SW = (unsigned short*)((char*)d_ws + (size_t)B * N * K1 * 2);
  float* out = (float*)d_out;

  vkern<<<dim3(B * N), dim3(64), 0, stream>>>(ctx, wt, V);
  swkern<<<dim3(B * N), dim3(256), 0, stream>>>(speed, uv_angle, acc_u, acc_v,
                                                uv_angleACC, angle, dist, SW, N);
  gemm_bt<0><<<dim3(N / 128, N / 128, B), dim3(256), 0, stream>>>(V, out, N, K1, 1.0f / (float)P);
  gemm_bt<1><<<dim3(N / 128, N / 128, B), dim3(256), 0, stream>>>(SW, Y, N, N, 1.4f / 20.0f);
  finkern<<<dim3(B * N), dim3(256), 0, stream>>>(Y, SW, out, N);
}

// Round 3
// 194.258 us; speedup vs baseline: 1.1141x; 1.1141x over previous
//
#include <hip/hip_runtime.h>
#include <hip/hip_bf16.h>
#include <math.h>

#define EPSV 1e-5f

typedef __attribute__((ext_vector_type(4))) float f32x4;
typedef __attribute__((ext_vector_type(8))) short bf16x8;
typedef __attribute__((ext_vector_type(4))) unsigned short u16x4;

__device__ __forceinline__ unsigned short f2b(float x) {
  union { float f; unsigned int u; } v; v.f = x;
  unsigned int r = v.u + 0x7FFFu + ((v.u >> 16) & 1u);
  return (unsigned short)(r >> 16);
}
__device__ __forceinline__ float b2f(unsigned short h) {
  union { float f; unsigned int u; } v; v.u = ((unsigned int)h) << 16;
  return v.f;
}

// block = 256 threads = 4 waves; sbuf must have 4 floats
__device__ __forceinline__ float block_reduce_sum(float v, float* sbuf) {
  #pragma unroll
  for (int off = 32; off; off >>= 1) v += __shfl_xor(v, off);
  __syncthreads();
  if ((threadIdx.x & 63) == 0) sbuf[threadIdx.x >> 6] = v;
  __syncthreads();
  return sbuf[0] + sbuf[1] + sbuf[2] + sbuf[3];
}

// ---------------- prep: V part (blk < BN) + SW part (blk >= BN) --------------
// V[b,n,p*128+d] = l2norm_d(context*w_p) bf16; SW[b,n,m] row-l2norm'd bf16.
__global__ __launch_bounds__(256) void prep(const float* __restrict__ ctx,
                                            const float* __restrict__ wt,
                                            const float* __restrict__ speed,
                                            const float* __restrict__ uva,
                                            const float* __restrict__ accu,
                                            const float* __restrict__ accv,
                                            const float* __restrict__ uvaACC,
                                            const float* __restrict__ angle,
                                            const float* __restrict__ dist,
                                            unsigned short* __restrict__ V,
                                            unsigned short* __restrict__ SW,
                                            int BN, int N) {
  __shared__ float sbuf[4];
  const int blk = blockIdx.x;
  if (blk < BN) {
    // ---- V: 4 waves x 4 p-per-wave; 16-lane group per p, 8 d per lane ----
    const int bn = blk;
    const int w = threadIdx.x >> 6;
    const int lane = threadIdx.x & 63;
    const int p = w * 4 + (lane >> 4);
    const int dl = (lane & 15) * 8;
    const float* c = ctx + (size_t)bn * 128;
    const f32x4 ca = *(const f32x4*)(c + dl);
    const f32x4 cb = *(const f32x4*)(c + dl + 4);
    const f32x4 wa = *(const f32x4*)(wt + p * 128 + dl);
    const f32x4 wb = *(const f32x4*)(wt + p * 128 + dl + 4);
    float a[8];
    float ss = 0.0f;
    #pragma unroll
    for (int i = 0; i < 4; ++i) {
      a[i] = ca[i] * wa[i];
      a[4 + i] = cb[i] * wb[i];
      ss += a[i] * a[i] + a[4 + i] * a[4 + i];
    }
    ss += __shfl_xor(ss, 1);
    ss += __shfl_xor(ss, 2);
    ss += __shfl_xor(ss, 4);
    ss += __shfl_xor(ss, 8);
    const float inv = 1.0f / fmaxf(sqrtf(ss), 1e-12f);
    bf16x8 o;
    #pragma unroll
    for (int i = 0; i < 8; ++i) o[i] = (short)f2b(a[i] * inv);
    *(bf16x8*)(V + (size_t)bn * 2048 + p * 128 + dl) = o;
  } else {
    // ---- SW: one (b,n) row per block, 4 consecutive m per thread ----
    const int bn = blk - BN;
    const int n = bn & (N - 1);
    const int t = threadIdx.x;
    const float ua = uva[bn];
    const float sp = fabsf(speed[bn]);
    const float au = accu[bn], av = accv[bn];
    const float ta = sqrtf(au * au + av * av + EPSV) * fabsf(cosf(uvaACC[bn] - ua));
    const f32x4 an = *(const f32x4*)(angle + (size_t)n * N + 4 * t);
    const f32x4 dv = *(const f32x4*)(dist + (size_t)n * N + 4 * t);
    float v[4];
    float ss = 0.0f;
    #pragma unroll
    for (int i = 0; i < 4; ++i) {
      float cv = cosf(an[i] - ua);
      if (4 * t + i == n) cv += 0.5f * ta;  // sigma * acc_part inside the abs
      v[i] = sp * fabsf(cv) / (dv[i] + EPSV);
      ss += v[i] * v[i];
    }
    ss = block_reduce_sum(ss, sbuf);
    const float inv = 1.0f / fmaxf(sqrtf(ss), 1e-12f);
    u16x4 o;
    #pragma unroll
    for (int i = 0; i < 4; ++i) o[i] = f2b(v[i] * inv);
    *(u16x4*)(SW + (size_t)bn * N + 4 * t) = o;
  }
}

// ---------------- fused GEMM: C = epilogue(scale * A · Aᵀ) -------------------
// 128x128 tile, BK=32, 4 waves (2x2), 2-phase double-buffered, one barrier/iter.
// Both-sides swizzle: global source 16B-chunk col ^= (row>>1)&3; read applies
// the same XOR. z (+zoff) < 8: attention (relu, V, K=2048) -> OUT;
// else: y (+EPS, SW, K=1024) -> Y.
__global__ __launch_bounds__(256) void gemm_fused(const unsigned short* __restrict__ V,
                                                  const unsigned short* __restrict__ SW,
                                                  float* __restrict__ OUT,
                                                  float* __restrict__ Y,
                                                  int N, int zoff) {
  __shared__ __align__(16) unsigned short As[2][128 * 32];
  __shared__ __align__(16) unsigned short Bs[2][128 * 32];
  const int z = blockIdx.z + zoff;
  const bool att = z < 8;
  const int b = att ? z : z - 8;
  const int K = att ? 2048 : 1024;
  const float scale = att ? (1.0f / 16.0f) : (1.4f / 20.0f);
  const unsigned short* Ab = att ? (V + (size_t)b * N * 2048)
                                 : (SW + (size_t)b * N * N);
  float* Cb = att ? (OUT + (size_t)b * N * N) : (Y + (size_t)b * N * N);

  const int n0 = blockIdx.x * 128;
  const int m0 = blockIdx.y * 128;
  const int tid = threadIdx.x;
  const int lane = tid & 63;
  const int wid = tid >> 6;
  const int wm = (wid >> 1) * 64;
  const int wn = (wid & 1) * 64;

  auto stage = [&](int buf, int k0) {
    #pragma unroll
    for (int i = 0; i < 2; ++i) {
      const int idx = i * 256 + tid;       // 16B chunk id, 0..511
      const int row = idx >> 2;            // 64B (32 bf16) per row
      const int cq = ((idx & 3) ^ ((row >> 1) & 3)) * 8;  // swizzled source col
      __builtin_amdgcn_global_load_lds(
          (const __attribute__((address_space(1))) unsigned int*)(Ab + (size_t)(m0 + row) * K + k0 + cq),
          (__attribute__((address_space(3))) unsigned int*)(&As[buf][idx * 8]), 16, 0, 0);
      __builtin_amdgcn_global_load_lds(
          (const __attribute__((address_space(1))) unsigned int*)(Ab + (size_t)(n0 + row) * K + k0 + cq),
          (__attribute__((address_space(3))) unsigned int*)(&Bs[buf][idx * 8]), 16, 0, 0);
    }
  };

  f32x4 acc[4][4] = {};
  stage(0, 0);
  __syncthreads();  // drains vmcnt: buf0 ready

  const int nk = K >> 5;
  for (int t = 0; t < nk; ++t) {
    const int cur = t & 1;
    if (t + 1 < nk) stage(cur ^ 1, (t + 1) << 5);  // prefetch overlaps compute

    bf16x8 af[4], bfr[4];
    const int c0 = lane >> 4;
    #pragma unroll
    for (int i = 0; i < 4; ++i) {
      const int r = wm + i * 16 + (lane & 15);
      af[i] = *(const bf16x8*)(&As[cur][r * 32 + ((c0 ^ ((r >> 1) & 3)) << 3)]);
    }
    #pragma unroll
    for (int j = 0; j < 4; ++j) {
      const int r = wn + j * 16 + (lane & 15);
      bfr[j] = *(const bf16x8*)(&Bs[cur][r * 32 + ((c0 ^ ((r >> 1) & 3)) << 3)]);
    }
    #pragma unroll
    for (int i = 0; i < 4; ++i)
      #pragma unroll
      for (int j = 0; j < 4; ++j)
        acc[i][j] = __builtin_amdgcn_mfma_f32_16x16x32_bf16(af[i], bfr[j], acc[i][j], 0, 0, 0);

    __syncthreads();  // one barrier/iter: drains stage vmcnt + read hazards
  }

  #pragma unroll
  for (int i = 0; i < 4; ++i) {
    #pragma unroll
    for (int r = 0; r < 4; ++r) {
      const int row = m0 + wm + i * 16 + (lane >> 4) * 4 + r;
      #pragma unroll
      for (int j = 0; j < 4; ++j) {
        const int col = n0 + wn + j * 16 + (lane & 15);
        float v = acc[i][j][r] * scale;
        v = att ? fmaxf(v, 0.0f) : (v + EPSV);
        Cb[(size_t)row * N + col] = v;
      }
    }
  }
}

// ---------------- finisher ---------------------------------------------------
// per (b,n) row: ynorm, t = |0.5*sw + sqrt(y/||y||)| + EPS, tnorm, out *= t/||t||
__global__ __launch_bounds__(256) void finkern(const float* __restrict__ Y,
                                               const unsigned short* __restrict__ SW,
                                               float* __restrict__ OUT,
                                               int N) {
  __shared__ float sbuf[4];
  const int bn = blockIdx.x;
  const int t = threadIdx.x;
  const float* y = Y + (size_t)bn * N;
  const unsigned short* sw = SW + (size_t)bn * N;
  float* o = OUT + (size_t)bn * N;

  const f32x4 yv = *(const f32x4*)(y + 4 * t);
  float ss = yv[0] * yv[0] + yv[1] * yv[1] + yv[2] * yv[2] + yv[3] * yv[3];
  ss = block_reduce_sum(ss, sbuf);
  const float invy = 1.0f / fmaxf(sqrtf(ss), 1e-12f);

  const u16x4 swv = *(const u16x4*)(sw + 4 * t);
  float tv[4];
  float st = 0.0f;
  #pragma unroll
  for (int i = 0; i < 4; ++i) {
    tv[i] = fabsf(0.5f * b2f(swv[i]) + sqrtf(yv[i] * invy)) + EPSV;
    st += tv[i] * tv[i];
  }
  st = block_reduce_sum(st, sbuf);
  const float invt = 1.0f / fmaxf(sqrtf(st), 1e-12f);

  f32x4 ov = *(f32x4*)(o + 4 * t);
  #pragma unroll
  for (int i = 0; i < 4; ++i) ov[i] *= tv[i] * invt;
  *(f32x4*)(o + 4 * t) = ov;
}

extern "C" void kernel_launch(void* const* d_in, const int* in_sizes, int n_in,
                              void* d_out, int out_size, void* d_ws, size_t ws_size,
                              hipStream_t stream) {
  const float* ctx        = (const float*)d_in[0];
  const float* acc_u      = (const float*)d_in[1];
  const float* acc_v      = (const float*)d_in[2];
  const float* uv_angle   = (const float*)d_in[3];
  const float* uv_angleACC= (const float*)d_in[4];
  const float* speed      = (const float*)d_in[5];
  // d_in[6] = isPhy (unused by the reference computation)
  const float* dist       = (const float*)d_in[7];
  const float* angle      = (const float*)d_in[8];
  const float* wt         = (const float*)d_in[9];

  const int B = 8, N = 1024, P = 16, D = 128;
  const int K1 = P * D;  // 2048
  const int BN = B * N;

  const size_t szV  = (size_t)BN * K1 * 2;   // 33.5 MB bf16
  const size_t szSW = (size_t)BN * N * 2;    // 16.8 MB bf16
  const size_t szY  = (size_t)BN * N * 4;    // 33.5 MB f32

  unsigned short* V  = (unsigned short*)d_ws;
  unsigned short* SW = (unsigned short*)((char*)d_ws + szV);
  float* out = (float*)d_out;

  prep<<<dim3(2 * BN), dim3(256), 0, stream>>>(ctx, wt, speed, uv_angle, acc_u,
                                               acc_v, uv_angleACC, angle, dist,
                                               V, SW, BN, N);

  if (ws_size >= szV + szSW + szY) {
    // fused: both GEMMs in one dispatch (Y has its own region)
    float* Yp = (float*)((char*)d_ws + szV + szSW);
    gemm_fused<<<dim3(N / 128, N / 128, 16), dim3(256), 0, stream>>>(V, SW, out, Yp, N, 0);
    finkern<<<dim3(BN), dim3(256), 0, stream>>>(Yp, SW, out, N);
  } else {
    // split fallback: Y aliases V (V fully consumed by the first launch)
    float* Yp = (float*)d_ws;
    gemm_fused<<<dim3(N / 128, N / 128, 8), dim3(256), 0, stream>>>(V, SW, out, Yp, N, 0);
    gemm_fused<<<dim3(N / 128, N / 128, 8), dim3(256), 0, stream>>>(V, SW, out, Yp, N, 8);
    finkern<<<dim3(BN), dim3(256), 0, stream>>>(Yp, SW, out, N);
  }
}

// Round 4
// 187.069 us; speedup vs baseline: 1.1569x; 1.0384x over previous
//
#include <hip/hip_runtime.h>
#include <hip/hip_bf16.h>
#include <math.h>

#define EPSV 1e-5f
#define AS1 __attribute__((address_space(1)))
#define AS3 __attribute__((address_space(3)))

typedef __attribute__((ext_vector_type(4))) float f32x4;
typedef __attribute__((ext_vector_type(8))) short bf16x8;
typedef __attribute__((ext_vector_type(4))) unsigned short u16x4;

__device__ __forceinline__ unsigned short f2b(float x) {
  union { float f; unsigned int u; } v; v.f = x;
  unsigned int r = v.u + 0x7FFFu + ((v.u >> 16) & 1u);
  return (unsigned short)(r >> 16);
}
__device__ __forceinline__ float b2f(unsigned short h) {
  union { float f; unsigned int u; } v; v.u = ((unsigned int)h) << 16;
  return v.f;
}

// block = 256 threads = 4 waves; sbuf must have 4 floats
__device__ __forceinline__ float block_reduce_sum(float v, float* sbuf) {
  #pragma unroll
  for (int off = 32; off; off >>= 1) v += __shfl_xor(v, off);
  __syncthreads();
  if ((threadIdx.x & 63) == 0) sbuf[threadIdx.x >> 6] = v;
  __syncthreads();
  return sbuf[0] + sbuf[1] + sbuf[2] + sbuf[3];
}

// ---------------- prep: V part (blk < BN) + SW part (blk >= BN) --------------
__global__ __launch_bounds__(256) void prep(const float* __restrict__ ctx,
                                            const float* __restrict__ wt,
                                            const float* __restrict__ speed,
                                            const float* __restrict__ uva,
                                            const float* __restrict__ accu,
                                            const float* __restrict__ accv,
                                            const float* __restrict__ uvaACC,
                                            const float* __restrict__ angle,
                                            const float* __restrict__ dist,
                                            unsigned short* __restrict__ V,
                                            unsigned short* __restrict__ SW,
                                            int BN, int N) {
  __shared__ float sbuf[4];
  const int blk = blockIdx.x;
  if (blk < BN) {
    const int bn = blk;
    const int w = threadIdx.x >> 6;
    const int lane = threadIdx.x & 63;
    const int p = w * 4 + (lane >> 4);
    const int dl = (lane & 15) * 8;
    const float* c = ctx + (size_t)bn * 128;
    const f32x4 ca = *(const f32x4*)(c + dl);
    const f32x4 cb = *(const f32x4*)(c + dl + 4);
    const f32x4 wa = *(const f32x4*)(wt + p * 128 + dl);
    const f32x4 wb = *(const f32x4*)(wt + p * 128 + dl + 4);
    float a[8];
    float ss = 0.0f;
    #pragma unroll
    for (int i = 0; i < 4; ++i) {
      a[i] = ca[i] * wa[i];
      a[4 + i] = cb[i] * wb[i];
      ss += a[i] * a[i] + a[4 + i] * a[4 + i];
    }
    ss += __shfl_xor(ss, 1);
    ss += __shfl_xor(ss, 2);
    ss += __shfl_xor(ss, 4);
    ss += __shfl_xor(ss, 8);
    const float inv = 1.0f / fmaxf(sqrtf(ss), 1e-12f);
    bf16x8 o;
    #pragma unroll
    for (int i = 0; i < 8; ++i) o[i] = (short)f2b(a[i] * inv);
    *(bf16x8*)(V + (size_t)bn * 2048 + p * 128 + dl) = o;
  } else {
    const int bn = blk - BN;
    const int n = bn & (N - 1);
    const int t = threadIdx.x;
    const float ua = uva[bn];
    const float sp = fabsf(speed[bn]);
    const float au = accu[bn], av = accv[bn];
    const float ta = sqrtf(au * au + av * av + EPSV) * fabsf(cosf(uvaACC[bn] - ua));
    const f32x4 an = *(const f32x4*)(angle + (size_t)n * N + 4 * t);
    const f32x4 dv = *(const f32x4*)(dist + (size_t)n * N + 4 * t);
    float v[4];
    float ss = 0.0f;
    #pragma unroll
    for (int i = 0; i < 4; ++i) {
      float cv = cosf(an[i] - ua);
      if (4 * t + i == n) cv += 0.5f * ta;
      v[i] = sp * fabsf(cv) / (dv[i] + EPSV);
      ss += v[i] * v[i];
    }
    ss = block_reduce_sum(ss, sbuf);
    const float inv = 1.0f / fmaxf(sqrtf(ss), 1e-12f);
    u16x4 o;
    #pragma unroll
    for (int i = 0; i < 4; ++i) o[i] = f2b(v[i] * inv);
    *(u16x4*)(SW + (size_t)bn * N + 4 * t) = o;
  }
}

// ---------------- 8-wave 256x256 phase-split GEMM: C = epi(scale * A·Aᵀ) -----
// BK=32, 4 phases per iter / 2 K-tiles, counted vmcnt(2) (never 0 mid-loop),
// raw s_barrier (no __syncthreads -> no vmcnt drain). Swizzle: 16B chunk
// pc = c ^ ((row>>1)&3), applied on global source AND LDS read (rule #21).
#define FENCE asm volatile("" ::: "memory")
__device__ __forceinline__ void barx() { FENCE; __builtin_amdgcn_s_barrier(); FENCE; }

#define QUAD(QI)                                                                 \
  { _Pragma("unroll") for (int i2 = 0; i2 < 4; ++i2) {                           \
      _Pragma("unroll") for (int j = 0; j < 4; ++j)                              \
        acc[(QI)*4 + i2][j] = __builtin_amdgcn_mfma_f32_16x16x32_bf16(           \
            af[i2], bf[j], acc[(QI)*4 + i2][j], 0, 0, 0); } }

__global__ __launch_bounds__(512, 2) void gemm8(const unsigned short* __restrict__ V,
                                                const unsigned short* __restrict__ SW,
                                                float* __restrict__ OUT,
                                                float* __restrict__ Y,
                                                int zmask, int zshift, int zoff) {
  __shared__ __align__(16) unsigned short As[2][256 * 32];
  __shared__ __align__(16) unsigned short Bs[2][256 * 32];
  const int bid = blockIdx.x;
  const int z = (bid & zmask) + zoff;     // batch-major over XCDs: z&7 = XCD
  const int tix = bid >> zshift;
  const int n0 = (tix & 3) * 256;
  const int m0 = (tix >> 2) * 256;
  const bool att = z < 8;
  const int b = att ? z : z - 8;
  const int K = att ? 2048 : 1024;
  const int NN = 1024;
  const float scale = att ? (1.0f / 16.0f) : (1.4f / 20.0f);
  const unsigned short* Ab = att ? (V + (size_t)b * NN * 2048) : (SW + (size_t)b * NN * NN);
  float* Cb = att ? (OUT + (size_t)b * NN * NN) : (Y + (size_t)b * NN * NN);

  const int tid = threadIdx.x;
  const int lane = tid & 63;
  const int wid = tid >> 6;          // 0..7 (2 row-waves x 4 col-waves)
  const int wm = (wid >> 2) * 128;
  const int wn = (wid & 3) * 64;
  const int fr = lane & 15;
  const int fc = lane >> 4;          // logical 16B chunk 0..3

  f32x4 acc[8][4] = {};
  bf16x8 af[4], bf[4];

  // stage one full operand tile (256x32 bf16 = 16KB) of K-tile kt into dstbuf
  auto stage = [&](unsigned short* dstbuf, int rbase, int kt) {
    const int k0 = kt << 5;
    #pragma unroll
    for (int e = 0; e < 2; ++e) {
      const int idx = e * 512 + tid;
      const int row = idx >> 2;
      const int pc = idx & 3;
      const int c = pc ^ ((row >> 1) & 3);
      __builtin_amdgcn_global_load_lds(
          (const AS1 unsigned int*)(Ab + (size_t)(rbase + row) * K + k0 + (c << 3)),
          (AS3 unsigned int*)(dstbuf + idx * 8), 16, 0, 0);
    }
  };
  auto lda4 = [&](const unsigned short* buf, int ib) {
    #pragma unroll
    for (int i2 = 0; i2 < 4; ++i2) {
      const int r = wm + (ib + i2) * 16 + fr;
      af[i2] = *(const bf16x8*)(buf + r * 32 + ((fc ^ ((r >> 1) & 3)) << 3));
    }
  };
  auto ldb4 = [&](const unsigned short* buf) {
    #pragma unroll
    for (int j = 0; j < 4; ++j) {
      const int r = wn + j * 16 + fr;
      bf[j] = *(const bf16x8*)(buf + r * 32 + ((fc ^ ((r >> 1) & 3)) << 3));
    }
  };

  const int nk = K >> 5;          // K-tiles (64 att / 32 y), always even
  const int niter = nk >> 1;

  // prologue: queue order B(0), A(0), B(1); wait oldest 4 -> tile0 resident
  stage(Bs[0], n0, 0);
  stage(As[0], m0, 0);
  stage(Bs[1], n0, 1);
  asm volatile("s_waitcnt vmcnt(2)" ::: "memory");
  barx();

  for (int k = 0; k < niter; ++k) {
    const int t0 = 2 * k, t1 = t0 + 1;
    // ---- ph0: compute tile t0 quadrant 0; prefetch A(t1) -> buf1
    lda4(As[0], 0); ldb4(Bs[0]);
    stage(As[1], m0, t1);
    barx();
    __builtin_amdgcn_s_setprio(1); QUAD(0); __builtin_amdgcn_s_setprio(0);
    asm volatile("s_waitcnt lgkmcnt(0)" ::: "memory");
    barx();
    // ---- ph1: tile t0 quadrant 1; prefetch B(t0+2) -> buf0 (B0 free since ph0)
    lda4(As[0], 4);
    if (t0 + 2 < nk) stage(Bs[0], n0, t0 + 2);
    barx();
    __builtin_amdgcn_s_setprio(1); QUAD(1); __builtin_amdgcn_s_setprio(0);
    asm volatile("s_waitcnt lgkmcnt(0)" ::: "memory");
    if (k + 1 < niter) { asm volatile("s_waitcnt vmcnt(2)" ::: "memory"); }
    else               { asm volatile("s_waitcnt vmcnt(0)" ::: "memory"); }
    barx();                       // after this: tile t1 fully resident
    // ---- ph2: compute tile t1 quadrant 0; prefetch A(t0+2) -> buf0
    lda4(As[1], 0); ldb4(Bs[1]);
    if (t0 + 2 < nk) stage(As[0], m0, t0 + 2);
    barx();
    __builtin_amdgcn_s_setprio(1); QUAD(0); __builtin_amdgcn_s_setprio(0);
    asm volatile("s_waitcnt lgkmcnt(0)" ::: "memory");
    barx();
    // ---- ph3: tile t1 quadrant 1; prefetch B(t1+2) -> buf1
    lda4(As[1], 4);
    if (t1 + 2 < nk) stage(Bs[1], n0, t1 + 2);
    barx();
    __builtin_amdgcn_s_setprio(1); QUAD(1); __builtin_amdgcn_s_setprio(0);
    asm volatile("s_waitcnt lgkmcnt(0)" ::: "memory");
    asm volatile("s_waitcnt vmcnt(2)" ::: "memory");
    barx();                       // after this: tile t0+2 fully resident
  }

  #pragma unroll
  for (int i = 0; i < 8; ++i) {
    #pragma unroll
    for (int r = 0; r < 4; ++r) {
      const int row = m0 + wm + i * 16 + fc * 4 + r;
      #pragma unroll
      for (int j = 0; j < 4; ++j) {
        const int col = n0 + wn + j * 16 + fr;
        float v = acc[i][j][r] * scale;
        v = att ? fmaxf(v, 0.0f) : (v + EPSV);
        Cb[(size_t)row * NN + col] = v;
      }
    }
  }
}

// ---------------- finisher ---------------------------------------------------
__global__ __launch_bounds__(256) void finkern(const float* __restrict__ Y,
                                               const unsigned short* __restrict__ SW,
                                               float* __restrict__ OUT,
                                               int N) {
  __shared__ float sbuf[4];
  const int bn = blockIdx.x;
  const int t = threadIdx.x;
  const float* y = Y + (size_t)bn * N;
  const unsigned short* sw = SW + (size_t)bn * N;
  float* o = OUT + (size_t)bn * N;

  const f32x4 yv = *(const f32x4*)(y + 4 * t);
  float ss = yv[0] * yv[0] + yv[1] * yv[1] + yv[2] * yv[2] + yv[3] * yv[3];
  ss = block_reduce_sum(ss, sbuf);
  const float invy = 1.0f / fmaxf(sqrtf(ss), 1e-12f);

  const u16x4 swv = *(const u16x4*)(sw + 4 * t);
  float tv[4];
  float st = 0.0f;
  #pragma unroll
  for (int i = 0; i < 4; ++i) {
    tv[i] = fabsf(0.5f * b2f(swv[i]) + sqrtf(yv[i] * invy)) + EPSV;
    st += tv[i] * tv[i];
  }
  st = block_reduce_sum(st, sbuf);
  const float invt = 1.0f / fmaxf(sqrtf(st), 1e-12f);

  f32x4 ov = *(f32x4*)(o + 4 * t);
  #pragma unroll
  for (int i = 0; i < 4; ++i) ov[i] *= tv[i] * invt;
  *(f32x4*)(o + 4 * t) = ov;
}

extern "C" void kernel_launch(void* const* d_in, const int* in_sizes, int n_in,
                              void* d_out, int out_size, void* d_ws, size_t ws_size,
                              hipStream_t stream) {
  const float* ctx        = (const float*)d_in[0];
  const float* acc_u      = (const float*)d_in[1];
  const float* acc_v      = (const float*)d_in[2];
  const float* uv_angle   = (const float*)d_in[3];
  const float* uv_angleACC= (const float*)d_in[4];
  const float* speed      = (const float*)d_in[5];
  // d_in[6] = isPhy (unused by the reference computation)
  const float* dist       = (const float*)d_in[7];
  const float* angle      = (const float*)d_in[8];
  const float* wt         = (const float*)d_in[9];

  const int B = 8, N = 1024, P = 16;
  const int K1 = P * 128;  // 2048
  const int BN = B * N;

  const size_t szV  = (size_t)BN * K1 * 2;   // 33.5 MB bf16
  const size_t szSW = (size_t)BN * N * 2;    // 16.8 MB bf16
  const size_t szY  = (size_t)BN * N * 4;    // 33.5 MB f32

  unsigned short* V  = (unsigned short*)d_ws;
  unsigned short* SW = (unsigned short*)((char*)d_ws + szV);
  float* out = (float*)d_out;

  prep<<<dim3(2 * BN), dim3(256), 0, stream>>>(ctx, wt, speed, uv_angle, acc_u,
                                               acc_v, uv_angleACC, angle, dist,
                                               V, SW, BN, N);

  if (ws_size >= szV + szSW + szY) {
    // fused: both GEMMs in one 256-block dispatch (1 block/CU, z&7 = XCD)
    float* Yp = (float*)((char*)d_ws + szV + szSW);
    gemm8<<<dim3(256), dim3(512), 0, stream>>>(V, SW, out, Yp, 15, 4, 0);
    finkern<<<dim3(BN), dim3(256), 0, stream>>>(Yp, SW, out, N);
  } else {
    // split fallback: Y aliases V (V fully consumed by the first launch)
    float* Yp = (float*)d_ws;
    gemm8<<<dim3(128), dim3(512), 0, stream>>>(V, SW, out, Yp, 7, 3, 0);
    gemm8<<<dim3(128), dim3(512), 0, stream>>>(V, SW, out, Yp, 7, 3, 8);
    finkern<<<dim3(BN), dim3(256), 0, stream>>>(Yp, SW, out, N);
  }
}

// Round 5
// 172.001 us; speedup vs baseline: 1.2582x; 1.0876x over previous
//
#include <hip/hip_runtime.h>
#include <hip/hip_bf16.h>
#include <math.h>

#define EPSV 1e-5f
#define AS1 __attribute__((address_space(1)))
#define AS3 __attribute__((address_space(3)))

typedef __attribute__((ext_vector_type(4))) float f32x4;
typedef __attribute__((ext_vector_type(8))) short bf16x8;
typedef __attribute__((ext_vector_type(4))) unsigned short u16x4;

__device__ __forceinline__ unsigned short f2b(float x) {
  union { float f; unsigned int u; } v; v.f = x;
  unsigned int r = v.u + 0x7FFFu + ((v.u >> 16) & 1u);
  return (unsigned short)(r >> 16);
}
__device__ __forceinline__ float b2f(unsigned short h) {
  union { float f; unsigned int u; } v; v.u = ((unsigned int)h) << 16;
  return v.f;
}

// block = 256 threads = 4 waves; sbuf must have 4 floats
__device__ __forceinline__ float block_reduce_sum(float v, float* sbuf) {
  #pragma unroll
  for (int off = 32; off; off >>= 1) v += __shfl_xor(v, off);
  __syncthreads();
  if ((threadIdx.x & 63) == 0) sbuf[threadIdx.x >> 6] = v;
  __syncthreads();
  return sbuf[0] + sbuf[1] + sbuf[2] + sbuf[3];
}

// ---------------- prep: V part (blk < BN) + SW part (blk >= BN) --------------
__global__ __launch_bounds__(256) void prep(const float* __restrict__ ctx,
                                            const float* __restrict__ wt,
                                            const float* __restrict__ speed,
                                            const float* __restrict__ uva,
                                            const float* __restrict__ accu,
                                            const float* __restrict__ accv,
                                            const float* __restrict__ uvaACC,
                                            const float* __restrict__ angle,
                                            const float* __restrict__ dist,
                                            unsigned short* __restrict__ V,
                                            unsigned short* __restrict__ SW,
                                            int BN, int N) {
  __shared__ float sbuf[4];
  const int blk = blockIdx.x;
  if (blk < BN) {
    const int bn = blk;
    const int w = threadIdx.x >> 6;
    const int lane = threadIdx.x & 63;
    const int p = w * 4 + (lane >> 4);
    const int dl = (lane & 15) * 8;
    const float* c = ctx + (size_t)bn * 128;
    const f32x4 ca = *(const f32x4*)(c + dl);
    const f32x4 cb = *(const f32x4*)(c + dl + 4);
    const f32x4 wa = *(const f32x4*)(wt + p * 128 + dl);
    const f32x4 wb = *(const f32x4*)(wt + p * 128 + dl + 4);
    float a[8];
    float ss = 0.0f;
    #pragma unroll
    for (int i = 0; i < 4; ++i) {
      a[i] = ca[i] * wa[i];
      a[4 + i] = cb[i] * wb[i];
      ss += a[i] * a[i] + a[4 + i] * a[4 + i];
    }
    ss += __shfl_xor(ss, 1);
    ss += __shfl_xor(ss, 2);
    ss += __shfl_xor(ss, 4);
    ss += __shfl_xor(ss, 8);
    const float inv = 1.0f / fmaxf(sqrtf(ss), 1e-12f);
    bf16x8 o;
    #pragma unroll
    for (int i = 0; i < 8; ++i) o[i] = (short)f2b(a[i] * inv);
    *(bf16x8*)(V + (size_t)bn * 2048 + p * 128 + dl) = o;
  } else {
    const int bn = blk - BN;
    const int n = bn & (N - 1);
    const int t = threadIdx.x;
    const float ua = uva[bn];
    const float sp = fabsf(speed[bn]);
    const float au = accu[bn], av = accv[bn];
    const float ta = sqrtf(au * au + av * av + EPSV) * fabsf(cosf(uvaACC[bn] - ua));
    const f32x4 an = *(const f32x4*)(angle + (size_t)n * N + 4 * t);
    const f32x4 dv = *(const f32x4*)(dist + (size_t)n * N + 4 * t);
    float v[4];
    float ss = 0.0f;
    #pragma unroll
    for (int i = 0; i < 4; ++i) {
      float cv = cosf(an[i] - ua);
      if (4 * t + i == n) cv += 0.5f * ta;
      v[i] = sp * fabsf(cv) / (dv[i] + EPSV);
      ss += v[i] * v[i];
    }
    ss = block_reduce_sum(ss, sbuf);
    const float inv = 1.0f / fmaxf(sqrtf(ss), 1e-12f);
    u16x4 o;
    #pragma unroll
    for (int i = 0; i < 4; ++i) o[i] = f2b(v[i] * inv);
    *(u16x4*)(SW + (size_t)bn * N + 4 * t) = o;
  }
}

// ---------------- 8-wave 128x256 GEMM: equal-work blocks, 3-buf ring ---------
// id<256: att tile (V, K=2048, relu/16 -> OUT f32).
// id>=256: y tile (SW, K=1024, *0.07+EPS -> Yb bf16).
// Per K-tile: {8 ds_read | stage(t+2) -> barrier -> 16 MFMA -> vmcnt(3) -> barrier}.
// vmcnt never 0 mid-loop. Swizzle (both sides): 16B chunk c = pc ^ ((row>>1)&3).
#define FENCE asm volatile("" ::: "memory")
__device__ __forceinline__ void barx() { FENCE; __builtin_amdgcn_s_barrier(); FENCE; }

__global__ __launch_bounds__(512, 4) void gemm8(const unsigned short* __restrict__ V,
                                                const unsigned short* __restrict__ SW,
                                                float* __restrict__ OUT,
                                                unsigned short* __restrict__ Yb,
                                                int boff) {
  __shared__ __align__(16) unsigned short As[3][128 * 32];
  __shared__ __align__(16) unsigned short Bs[3][256 * 32];
  const int id = blockIdx.x + boff;
  const bool att = id < 256;
  const int r = att ? id : id - 256;
  const int b = r & 7;                 // batch -> XCD affinity
  const int tile = r >> 3;             // 0..31
  const int m0 = (tile & 7) * 128;
  const int n0 = (tile >> 3) * 256;
  const int K = att ? 2048 : 1024;
  const int NN = 1024;
  const unsigned short* Ab = att ? (V + (size_t)b * NN * 2048) : (SW + (size_t)b * NN * NN);

  const int tid = threadIdx.x;
  const int lane = tid & 63;
  const int wid = tid >> 6;            // 8 waves: 2 (M) x 4 (N)
  const int wm = (wid >> 2) * 64;      // 0,64
  const int wn = (wid & 3) * 64;       // 0..192
  const int fr = lane & 15;
  const int fc = lane >> 4;
  // (row>>1)&3 == (fr>>1)&3 for all our rows (offsets are multiples of 16)
  const int rsw = (fc ^ ((fr >> 1) & 3)) << 3;   // lane-constant read swizzle (shorts)

  f32x4 acc[4][4] = {};
  bf16x8 af[4], bf[4];

  auto stage = [&](int sb, int kt) {   // 3 x global_load_lds (A:1, B:2)
    const int k0 = kt << 5;
    {
      const int row = tid >> 2;
      const int c = (tid & 3) ^ ((row >> 1) & 3);
      __builtin_amdgcn_global_load_lds(
          (const AS1 unsigned int*)(Ab + (size_t)(m0 + row) * K + k0 + (c << 3)),
          (AS3 unsigned int*)(&As[sb][tid * 8]), 16, 0, 0);
    }
    #pragma unroll
    for (int e = 0; e < 2; ++e) {
      const int idx = e * 512 + tid;
      const int row = idx >> 2;
      const int c = (idx & 3) ^ ((row >> 1) & 3);
      __builtin_amdgcn_global_load_lds(
          (const AS1 unsigned int*)(Ab + (size_t)(n0 + row) * K + k0 + (c << 3)),
          (AS3 unsigned int*)(&Bs[sb][idx * 8]), 16, 0, 0);
    }
  };

  const int nk = K >> 5;               // 64 (att) / 32 (y)

  stage(0, 0);
  stage(1, 1);
  asm volatile("s_waitcnt vmcnt(3)" ::: "memory");   // tile 0 resident
  barx();

  int rd = 0;
  for (int t = 0; t < nk; ++t) {
    const unsigned short* Ar = As[rd];
    const unsigned short* Br = Bs[rd];
    #pragma unroll
    for (int i = 0; i < 4; ++i)
      af[i] = *(const bf16x8*)(Ar + (wm + i * 16 + fr) * 32 + rsw);
    #pragma unroll
    for (int j = 0; j < 4; ++j)
      bf[j] = *(const bf16x8*)(Br + (wn + j * 16 + fr) * 32 + rsw);

    if (t + 2 < nk) {
      int st = rd + 2; if (st >= 3) st -= 3;   // == (t+2)%3; last read at t-1
      stage(st, t + 2);
    }
    barx();
    asm volatile("s_waitcnt lgkmcnt(0)" ::: "memory");
    __builtin_amdgcn_s_setprio(1);
    #pragma unroll
    for (int i = 0; i < 4; ++i)
      #pragma unroll
      for (int j = 0; j < 4; ++j)
        acc[i][j] = __builtin_amdgcn_mfma_f32_16x16x32_bf16(af[i], bf[j], acc[i][j], 0, 0, 0);
    __builtin_amdgcn_s_setprio(0);
    if (t + 2 < nk)      { asm volatile("s_waitcnt vmcnt(3)" ::: "memory"); }  // t+1 resident
    else if (t + 1 < nk) { asm volatile("s_waitcnt vmcnt(0)" ::: "memory"); }
    barx();
    rd = (rd + 1 == 3) ? 0 : rd + 1;
  }

  if (att) {
    float* Cb = OUT + (size_t)b * NN * NN;
    #pragma unroll
    for (int i = 0; i < 4; ++i)
      #pragma unroll
      for (int rr = 0; rr < 4; ++rr) {
        const int row = m0 + wm + i * 16 + fc * 4 + rr;
        #pragma unroll
        for (int j = 0; j < 4; ++j) {
          const int col = n0 + wn + j * 16 + fr;
          Cb[(size_t)row * NN + col] = fmaxf(acc[i][j][rr] * (1.0f / 16.0f), 0.0f);
        }
      }
  } else {
    unsigned short* Cb = Yb + (size_t)b * NN * NN;
    #pragma unroll
    for (int i = 0; i < 4; ++i)
      #pragma unroll
      for (int rr = 0; rr < 4; ++rr) {
        const int row = m0 + wm + i * 16 + fc * 4 + rr;
        #pragma unroll
        for (int j = 0; j < 4; ++j) {
          const int col = n0 + wn + j * 16 + fr;
          Cb[(size_t)row * NN + col] = f2b(acc[i][j][rr] * (1.4f / 20.0f) + EPSV);
        }
      }
  }
}

// ---------------- finisher (Y in bf16) ---------------------------------------
__global__ __launch_bounds__(256) void finkern(const unsigned short* __restrict__ Yb,
                                               const unsigned short* __restrict__ SW,
                                               float* __restrict__ OUT,
                                               int N) {
  __shared__ float sbuf[4];
  const int bn = blockIdx.x;
  const int t = threadIdx.x;
  const unsigned short* y = Yb + (size_t)bn * N;
  const unsigned short* sw = SW + (size_t)bn * N;
  float* o = OUT + (size_t)bn * N;

  const u16x4 yraw = *(const u16x4*)(y + 4 * t);
  float yv[4];
  float ss = 0.0f;
  #pragma unroll
  for (int i = 0; i < 4; ++i) {
    yv[i] = b2f(yraw[i]);
    ss += yv[i] * yv[i];
  }
  ss = block_reduce_sum(ss, sbuf);
  const float invy = 1.0f / fmaxf(sqrtf(ss), 1e-12f);

  const u16x4 swv = *(const u16x4*)(sw + 4 * t);
  float tv[4];
  float st = 0.0f;
  #pragma unroll
  for (int i = 0; i < 4; ++i) {
    tv[i] = fabsf(0.5f * b2f(swv[i]) + sqrtf(yv[i] * invy)) + EPSV;
    st += tv[i] * tv[i];
  }
  st = block_reduce_sum(st, sbuf);
  const float invt = 1.0f / fmaxf(sqrtf(st), 1e-12f);

  f32x4 ov = *(f32x4*)(o + 4 * t);
  #pragma unroll
  for (int i = 0; i < 4; ++i) ov[i] *= tv[i] * invt;
  *(f32x4*)(o + 4 * t) = ov;
}

extern "C" void kernel_launch(void* const* d_in, const int* in_sizes, int n_in,
                              void* d_out, int out_size, void* d_ws, size_t ws_size,
                              hipStream_t stream) {
  const float* ctx        = (const float*)d_in[0];
  const float* acc_u      = (const float*)d_in[1];
  const float* acc_v      = (const float*)d_in[2];
  const float* uv_angle   = (const float*)d_in[3];
  const float* uv_angleACC= (const float*)d_in[4];
  const float* speed      = (const float*)d_in[5];
  // d_in[6] = isPhy (unused by the reference computation)
  const float* dist       = (const float*)d_in[7];
  const float* angle      = (const float*)d_in[8];
  const float* wt         = (const float*)d_in[9];

  const int B = 8, N = 1024, P = 16;
  const int K1 = P * 128;  // 2048
  const int BN = B * N;

  const size_t szV  = (size_t)BN * K1 * 2;   // 33.5 MB bf16
  const size_t szSW = (size_t)BN * N * 2;    // 16.8 MB bf16
  const size_t szYb = (size_t)BN * N * 2;    // 16.8 MB bf16

  unsigned short* V  = (unsigned short*)d_ws;
  unsigned short* SW = (unsigned short*)((char*)d_ws + szV);
  float* out = (float*)d_out;

  prep<<<dim3(2 * BN), dim3(256), 0, stream>>>(ctx, wt, speed, uv_angle, acc_u,
                                               acc_v, uv_angleACC, angle, dist,
                                               V, SW, BN, N);

  if (ws_size >= szV + szSW + szYb) {
    // fused: 512 equal-work blocks = 2 resident blocks per CU (1 att + 1 y)
    unsigned short* Yp = (unsigned short*)((char*)d_ws + szV + szSW);
    gemm8<<<dim3(512), dim3(512), 0, stream>>>(V, SW, out, Yp, 0);
    finkern<<<dim3(BN), dim3(256), 0, stream>>>(Yp, SW, out, N);
  } else {
    // split fallback: Yb aliases V (V fully consumed by the att dispatch)
    unsigned short* Yp = (unsigned short*)d_ws;
    gemm8<<<dim3(256), dim3(512), 0, stream>>>(V, SW, out, Yp, 0);
    gemm8<<<dim3(256), dim3(512), 0, stream>>>(V, SW, out, Yp, 256);
    finkern<<<dim3(BN), dim3(256), 0, stream>>>(Yp, SW, out, N);
  }
}